// Round 3
// baseline (559.380 us; speedup 1.0000x reference)
//
#include <hip/hip_runtime.h>
#include <cstdint>

typedef __bf16 bf16x8 __attribute__((ext_vector_type(8)));
typedef float f32x4 __attribute__((ext_vector_type(4)));
typedef unsigned int u32x4 __attribute__((ext_vector_type(4)));
typedef unsigned int u32x2 __attribute__((ext_vector_type(2)));
typedef unsigned short u16;
typedef unsigned int u32;

// Problem constants (fixed by reference)
#define HH 128
#define WW 128
#define CC 64
#define QQ 65536
#define BB 4

// LDS activation row stride in u16: 256 features + 8 pad.
// 264 u16 = 528 B = 132 words; 132 mod 32 = 4 -> row r rotates banks by 4r,
// giving the same conflict-free distribution as the old XOR swizzle while
// keeping addresses ADDITIVE (ds offset immediates, no per-access VALU).
#define RS 264

// Packed-weight offsets in bf16 elements inside d_ws (kt-major fragment order)
#define L0_OFF 0        // 3 kt x 16 nt x 512  = 24576
#define L1_OFF 24576    // 8 x 16 x 512 = 65536
#define L2_OFF 90112
#define L3_OFF 155648
#define W4_OFF 221184   // 8 kt x 1 nt x 512 = 4096
#define FEATT_BYTE_OFF 524288u  // featT: 4*128*128*64 bf16 = 8388608 B

// ---------------------------------------------------------------------------
// Pack w0..w3 (+ w4 zero-padded to 16 cols) into MFMA fragment order (bf16),
// kt-major: tile index = kt*NT + nt.  Fragment (nt,kt): lane l, j=0..7 holds
//   W[kt*32 + (l>>4)*8 + j][nt*16 + (l&15)]
// Serves as B-frag of W == A-frag of W^T.  Layer 0 K padded 68 -> 96.
// ---------------------------------------------------------------------------
__global__ void pack_weights(const float* __restrict__ w0,
                             const float* __restrict__ w1,
                             const float* __restrict__ w2,
                             const float* __restrict__ w3,
                             const float* __restrict__ w4,
                             u16* __restrict__ ws_us) {
    int bid = blockIdx.x;
    int lane = threadIdx.x;  // 64
    int tile, nk, off, Ksrc, Ncols, NT;
    const float* w;
    if (bid < 48)       { tile = bid;       nk = 3; off = L0_OFF; w = w0; Ksrc = 68;  Ncols = 256; NT = 16; }
    else if (bid < 176) { tile = bid - 48;  nk = 8; off = L1_OFF; w = w1; Ksrc = 256; Ncols = 256; NT = 16; }
    else if (bid < 304) { tile = bid - 176; nk = 8; off = L2_OFF; w = w2; Ksrc = 256; Ncols = 256; NT = 16; }
    else if (bid < 432) { tile = bid - 304; nk = 8; off = L3_OFF; w = w3; Ksrc = 256; Ncols = 256; NT = 16; }
    else                { tile = bid - 432; nk = 8; off = W4_OFF; w = w4; Ksrc = 256; Ncols = 3;   NT = 1;  }
    int kt = tile % nk;
    int nt = tile / nk;
    int n = nt * 16 + (lane & 15);
    int kbase = kt * 32 + (lane >> 4) * 8;
    unsigned int d[4];
    for (int i = 0; i < 4; ++i) {
        unsigned int lo, hi;
        {
            int k = kbase + 2 * i;
            float x = (k < Ksrc && n < Ncols) ? w[k * Ncols + n] : 0.0f;
            __bf16 hb = (__bf16)x;
            lo = (unsigned int)__builtin_bit_cast(u16, hb);
        }
        {
            int k = kbase + 2 * i + 1;
            float x = (k < Ksrc && n < Ncols) ? w[k * Ncols + n] : 0.0f;
            __bf16 hb = (__bf16)x;
            hi = (unsigned int)__builtin_bit_cast(u16, hb);
        }
        d[i] = lo | (hi << 16);
    }
    u32x4 pk = { d[0], d[1], d[2], d[3] };
    int dst = off + (kt * NT + nt) * 512 + lane * 8;  // bf16 elems, 16B aligned
    *reinterpret_cast<u32x4*>(ws_us + dst) = pk;
}

// ---------------------------------------------------------------------------
// feat [B,C,H,W] fp32 -> featT [B,H,W,C] bf16 (per-pixel gather = one
// contiguous 128B read). One block per (b, y) row; LDS transpose.
// ---------------------------------------------------------------------------
__global__ void prep_featT(const float* __restrict__ feat, u16* __restrict__ featT) {
    __shared__ u16 tile[128 * 66];
    int bid = blockIdx.x;
    int b = bid >> 7, y = bid & 127;
    for (int idx = threadIdx.x; idx < CC * WW; idx += 256) {
        int c = idx >> 7, x = idx & 127;
        float v = feat[(((b * CC + c) * HH + y) * WW) + x];
        __bf16 hb = (__bf16)v;
        tile[x * 66 + c] = __builtin_bit_cast(u16, hb);
    }
    __syncthreads();
    for (int idx = threadIdx.x; idx < 2048; idx += 256) {
        int x = idx >> 4, c4 = (idx & 15) * 4;
        const u16* src = tile + x * 66 + c4;
        u32x2 d;
        d[0] = (unsigned int)src[0] | ((unsigned int)src[1] << 16);
        d[1] = (unsigned int)src[2] | ((unsigned int)src[3] << 16);
        *reinterpret_cast<u32x2*>(featT + ((b * HH + y) * WW + x) * CC + c4) = d;
    }
}

// ---------------------------------------------------------------------------
// Preload a layer's kt=0 weight fragments (issued BEFORE the barrier so L2
// latency overlaps the barrier wait; plain VGPR loads cross s_barrier).
// ---------------------------------------------------------------------------
__device__ __forceinline__ void preload_w(u32x4 wpre[4], const u32x4* __restrict__ wbase,
                                          int voff) {
#pragma unroll
    for (int fi = 0; fi < 4; ++fi)
        wpre[fi] = wbase[voff + fi * 64];
}

// ---------------------------------------------------------------------------
// Transposed GEMM layer: Y^T = W^T[256,K] * X^T[K,64].  A = packed W frags
// (global/L2, kt-major), B = X rows from LDS.  Wave owns feature-tiles
// wave*4..+3 for all 4 sample-tiles.  C layout: lane holds sample
// st*16+(lane&15), features ft*16+(lane>>4)*4+r (contiguous) -> ds_write_b64.
// All LDS addresses: one base VGPR + compile-time immediates.
// ---------------------------------------------------------------------------
template <int NK>
__device__ __forceinline__ void gemm_layer(const u16* __restrict__ src,
                                           u16* __restrict__ dst,
                                           const u32x4* __restrict__ wbase,
                                           const float* __restrict__ bias,
                                           int wave, int lane,
                                           const u32x4 wpre[4]) {
    f32x4 acc[4][4] = {};
    const int l15 = lane & 15;
    const int qd = lane >> 4;
    const int voff = wave * 256 + lane;           // u32x4 index, fi=0 fragment
    const u16* xb = src + l15 * RS + qd * 8;      // one LDS base for ALL reads
    u16* db = dst + l15 * RS + wave * 64 + qd * 4;

    u32x4 wq[3][4];
#pragma unroll
    for (int fi = 0; fi < 4; ++fi) wq[0][fi] = wpre[fi];
    if (NK > 1) {
        const u32x4* wn = wbase + 1024;
#pragma unroll
        for (int fi = 0; fi < 4; ++fi) wq[1][fi] = wn[voff + fi * 64];
    }

    bf16x8 xc[4], xn[4];
#pragma unroll
    for (int st = 0; st < 4; ++st)
        xc[st] = __builtin_bit_cast(bf16x8,
            *reinterpret_cast<const u32x4*>(xb + st * 16 * RS));

#pragma unroll
    for (int kt = 0; kt < NK; ++kt) {
        if (kt + 2 < NK) {
            const u32x4* wn = wbase + (kt + 2) * 1024;
#pragma unroll
            for (int fi = 0; fi < 4; ++fi)
                wq[(kt + 2) % 3][fi] = wn[voff + fi * 64];
        }
        if (kt + 1 < NK) {
#pragma unroll
            for (int st = 0; st < 4; ++st)
                xn[st] = __builtin_bit_cast(bf16x8,
                    *reinterpret_cast<const u32x4*>(xb + st * 16 * RS + (kt + 1) * 32));
        }
#pragma unroll
        for (int fi = 0; fi < 4; ++fi) {
            bf16x8 wf = __builtin_bit_cast(bf16x8, wq[kt % 3][fi]);
#pragma unroll
            for (int st = 0; st < 4; ++st)
                acc[fi][st] = __builtin_amdgcn_mfma_f32_16x16x32_bf16(
                    wf, xc[st], acc[fi][st], 0, 0, 0);
        }
        if (kt + 1 < NK) {
#pragma unroll
            for (int st = 0; st < 4; ++st) xc[st] = xn[st];
        }
    }

    // Epilogue: bias + ReLU + bf16, one ds_write_b64 per (fi,st), imm offsets.
#pragma unroll
    for (int fi = 0; fi < 4; ++fi) {
        int fbase = (wave * 4 + fi) * 16 + qd * 4;
        f32x4 bv = *reinterpret_cast<const f32x4*>(bias + fbase);
#pragma unroll
        for (int st = 0; st < 4; ++st) {
            float v0 = fmaxf(acc[fi][st][0] + bv[0], 0.0f);
            float v1 = fmaxf(acc[fi][st][1] + bv[1], 0.0f);
            float v2 = fmaxf(acc[fi][st][2] + bv[2], 0.0f);
            float v3 = fmaxf(acc[fi][st][3] + bv[3], 0.0f);
            __bf16 h0 = (__bf16)v0, h1 = (__bf16)v1, h2 = (__bf16)v2, h3 = (__bf16)v3;
            u32x2 d;
            d[0] = (u32)__builtin_bit_cast(u16, h0) | ((u32)__builtin_bit_cast(u16, h1) << 16);
            d[1] = (u32)__builtin_bit_cast(u16, h2) | ((u32)__builtin_bit_cast(u16, h3) << 16);
            *reinterpret_cast<u32x2*>(db + st * 16 * RS + fi * 16) = d;
        }
    }
}

// ---------------------------------------------------------------------------
// Main fused kernel: 16 queries x 4 branches = 64 rows (samples) per block.
// ---------------------------------------------------------------------------
__global__ __launch_bounds__(256, 2) void liif_main(
    const float* __restrict__ coord, const float* __restrict__ cell,
    const float* __restrict__ b0, const float* __restrict__ b1,
    const float* __restrict__ b2, const float* __restrict__ b3,
    const float* __restrict__ b4,
    const u16* __restrict__ wpack, const u16* __restrict__ featT,
    float* __restrict__ out) {
    __shared__ u16 bufA[64 * RS];
    __shared__ u16 bufB[64 * RS];
    __shared__ float areasLDS[64];

    const int t = threadIdx.x;
    const int wave = t >> 6, lane = t & 63;
    const int row = t >> 2, p = t & 3;

    // ---- stage X0 (branch math + feature gather), 4 threads per row ----
    const int bq = blockIdx.x * 16 + (row >> 2);
    const int v = row & 3;
    const int b = bq >> 16;  // Q = 65536
    const float c0 = coord[bq * 2 + 0];
    const float c1 = coord[bq * 2 + 1];
    const float rc0 = cell[bq * 2 + 0] * 128.0f;
    const float rc1 = cell[bq * 2 + 1] * 128.0f;
    const float eps = 1e-6f;
    const float sx = ((v & 2) ? 0.0078125f : -0.0078125f) + eps;
    const float sy = ((v & 1) ? 0.0078125f : -0.0078125f) + eps;
    float cs0 = fminf(fmaxf(c0 + sx, -1.0f + eps), 1.0f - eps);
    float cs1 = fminf(fmaxf(c1 + sy, -1.0f + eps), 1.0f - eps);
    float fy = fminf(fmaxf(floorf((cs0 + 1.0f) * 64.0f), 0.0f), 127.0f);
    float fx = fminf(fmaxf(floorf((cs1 + 1.0f) * 64.0f), 0.0f), 127.0f);
    int iy = (int)fy, ix = (int)fx;
    float qc0 = -1.0f + (2.0f * fy + 1.0f) * 0.0078125f;
    float qc1 = -1.0f + (2.0f * fx + 1.0f) * 0.0078125f;
    float rel0 = (c0 - qc0) * 128.0f;
    float rel1 = (c1 - qc1) * 128.0f;
    float area = fabsf(rel0 * rel1) + 1e-9f;

    {
        const u16* fr = featT + (((b * HH + iy) * WW + ix) * CC) + p * 16;
        u32x4 f0 = *reinterpret_cast<const u32x4*>(fr);
        u32x4 f1 = *reinterpret_cast<const u32x4*>(fr + 8);
        u16* sb = bufA + row * RS;
        *reinterpret_cast<u32x4*>(sb + p * 16) = f0;
        *reinterpret_cast<u32x4*>(sb + p * 16 + 8) = f1;
        u32x4 e = { 0u, 0u, 0u, 0u };
        if (p == 0) {
            __bf16 h0 = (__bf16)rel0, h1 = (__bf16)rel1, h2 = (__bf16)rc0, h3 = (__bf16)rc1;
            e[0] = (u32)__builtin_bit_cast(u16, h0) | ((u32)__builtin_bit_cast(u16, h1) << 16);
            e[1] = (u32)__builtin_bit_cast(u16, h2) | ((u32)__builtin_bit_cast(u16, h3) << 16);
            areasLDS[row] = area;
        }
        *reinterpret_cast<u32x4*>(sb + 64 + p * 8) = e;  // features 64..95
    }

    const u32x4* wp = reinterpret_cast<const u32x4*>(wpack);
    const u32x4* wp0 = wp + (L0_OFF / 8);
    const u32x4* wp1 = wp + (L1_OFF / 8);
    const u32x4* wp2 = wp + (L2_OFF / 8);
    const u32x4* wp3 = wp + (L3_OFF / 8);
    const u32x4* wp4 = wp + (W4_OFF / 8);
    const int voff = wave * 256 + lane;

    u32x4 wpre[4];
    preload_w(wpre, wp0, voff);
    __syncthreads();
    gemm_layer<3>(bufA, bufB, wp0, b0, wave, lane, wpre);
    preload_w(wpre, wp1, voff);
    __syncthreads();
    gemm_layer<8>(bufB, bufA, wp1, b1, wave, lane, wpre);
    preload_w(wpre, wp2, voff);
    __syncthreads();
    gemm_layer<8>(bufA, bufB, wp2, b2, wave, lane, wpre);
    preload_w(wpre, wp3, voff);
    __syncthreads();
    gemm_layer<8>(bufB, bufA, wp3, b3, wave, lane, wpre);

    // preload ALL final-layer fragments (32 VGPRs) across the barrier
    u32x4 w4f[8];
#pragma unroll
    for (int kt = 0; kt < 8; ++kt) w4f[kt] = wp4[kt * 64 + lane];
    __syncthreads();

    // ---- final layer 256->3 via MFMA; wave handles sample-tile st = wave ----
    const int l15 = lane & 15;
    const int qd = lane >> 4;
    const u16* xb = bufA + (wave * 16 + l15) * RS + qd * 8;
    f32x4 accf = {};
#pragma unroll
    for (int kt = 0; kt < 8; ++kt) {
        bf16x8 x = __builtin_bit_cast(bf16x8,
            *reinterpret_cast<const u32x4*>(xb + kt * 32));
        accf = __builtin_amdgcn_mfma_f32_16x16x32_bf16(
            __builtin_bit_cast(bf16x8, w4f[kt]), x, accf, 0, 0, 0);
    }
    // lane (qd==0) holds pred[0..2] in accf[0..2] for sample = wave*16 + l15.
    float a = areasLDS[wave * 16 + l15];
    float a1 = a + __shfl_xor(a, 1);
    float asum = a1 + __shfl_xor(a1, 2);
    float aopp = __shfl_xor(a, 3);  // diagonal swap 0<->3, 1<->2
    float wgt = aopp / asum;
    float o0 = (accf[0] + b4[0]) * wgt;
    float o1 = (accf[1] + b4[1]) * wgt;
    float o2 = (accf[2] + b4[2]) * wgt;
    o0 += __shfl_xor(o0, 1); o0 += __shfl_xor(o0, 2);
    o1 += __shfl_xor(o1, 1); o1 += __shfl_xor(o1, 2);
    o2 += __shfl_xor(o2, 1); o2 += __shfl_xor(o2, 2);

    if (qd == 0 && (l15 & 3) == 0) {
        int obq = blockIdx.x * 16 + wave * 4 + (l15 >> 2);
        out[obq * 3 + 0] = o0;
        out[obq * 3 + 1] = o1;
        out[obq * 3 + 2] = o2;
    }
}

// ---------------------------------------------------------------------------
extern "C" void kernel_launch(void* const* d_in, const int* in_sizes, int n_in,
                              void* d_out, int out_size, void* d_ws, size_t ws_size,
                              hipStream_t stream) {
    const float* feat  = (const float*)d_in[0];
    const float* coord = (const float*)d_in[1];
    const float* cell  = (const float*)d_in[2];
    const float* w0 = (const float*)d_in[3];
    const float* b0 = (const float*)d_in[4];
    const float* w1 = (const float*)d_in[5];
    const float* b1 = (const float*)d_in[6];
    const float* w2 = (const float*)d_in[7];
    const float* b2 = (const float*)d_in[8];
    const float* w3 = (const float*)d_in[9];
    const float* b3 = (const float*)d_in[10];
    const float* w4 = (const float*)d_in[11];
    const float* b4 = (const float*)d_in[12];

    u16* ws_us = (u16*)d_ws;
    u16* featT = (u16*)((char*)d_ws + FEATT_BYTE_OFF);
    // ws need: 524288 + 8388608 = 8912896 bytes

    hipLaunchKernelGGL(pack_weights, dim3(440), dim3(64), 0, stream,
                       w0, w1, w2, w3, w4, ws_us);
    hipLaunchKernelGGL(prep_featT, dim3(BB * HH), dim3(256), 0, stream, feat, featT);
    hipLaunchKernelGGL(liif_main, dim3((BB * QQ) / 16), dim3(256), 0, stream,
                       coord, cell, b0, b1, b2, b3, b4, ws_us, featT,
                       (float*)d_out);
}

// Round 4
// 525.808 us; speedup vs baseline: 1.0638x; 1.0638x over previous
//
#include <hip/hip_runtime.h>
#include <cstdint>

typedef __bf16 bf16x8 __attribute__((ext_vector_type(8)));
typedef float f32x4 __attribute__((ext_vector_type(4)));
typedef unsigned int u32x4 __attribute__((ext_vector_type(4)));
typedef unsigned int u32x2 __attribute__((ext_vector_type(2)));
typedef unsigned short u16;
typedef unsigned int u32;

// Problem constants (fixed by reference)
#define HH 128
#define WW 128
#define CC 64
#define QQ 65536
#define BB 4

// LDS activation row stride in u16: 256 features + 8 pad.
// 264 u16 = 528 B = 132 words; 132 mod 32 = 4 -> row r rotates banks by 4r;
// all addresses stay ADDITIVE (ds offset immediates, no per-access VALU).
#define RS 264

// Packed-weight offsets in bf16 elements inside d_ws (kt-major fragment order)
#define L0_OFF 0        // 3 kt x 16 nt x 512  = 24576
#define L1_OFF 24576    // 8 x 16 x 512 = 65536
#define L2_OFF 90112
#define L3_OFF 155648
#define W4_OFF 221184   // 8 kt x 1 nt x 512 = 4096
#define FEATT_BYTE_OFF 524288u  // featT: 4*128*128*64 bf16 = 8388608 B

// ---------------------------------------------------------------------------
// Pack w0..w3 (+ w4 zero-padded to 16 cols) into MFMA fragment order (bf16),
// kt-major: tile index = kt*NT + nt.  Fragment (nt,kt): lane l, j=0..7 holds
//   W[kt*32 + (l>>4)*8 + j][nt*16 + (l&15)]
// Serves as B-frag of W == A-frag of W^T.  Layer 0 K padded 68 -> 96.
// ---------------------------------------------------------------------------
__global__ void pack_weights(const float* __restrict__ w0,
                             const float* __restrict__ w1,
                             const float* __restrict__ w2,
                             const float* __restrict__ w3,
                             const float* __restrict__ w4,
                             u16* __restrict__ ws_us) {
    int bid = blockIdx.x;
    int lane = threadIdx.x;  // 64
    int tile, nk, off, Ksrc, Ncols, NT;
    const float* w;
    if (bid < 48)       { tile = bid;       nk = 3; off = L0_OFF; w = w0; Ksrc = 68;  Ncols = 256; NT = 16; }
    else if (bid < 176) { tile = bid - 48;  nk = 8; off = L1_OFF; w = w1; Ksrc = 256; Ncols = 256; NT = 16; }
    else if (bid < 304) { tile = bid - 176; nk = 8; off = L2_OFF; w = w2; Ksrc = 256; Ncols = 256; NT = 16; }
    else if (bid < 432) { tile = bid - 304; nk = 8; off = L3_OFF; w = w3; Ksrc = 256; Ncols = 256; NT = 16; }
    else                { tile = bid - 432; nk = 8; off = W4_OFF; w = w4; Ksrc = 256; Ncols = 3;   NT = 1;  }
    int kt = tile % nk;
    int nt = tile / nk;
    int n = nt * 16 + (lane & 15);
    int kbase = kt * 32 + (lane >> 4) * 8;
    unsigned int d[4];
    for (int i = 0; i < 4; ++i) {
        unsigned int lo, hi;
        {
            int k = kbase + 2 * i;
            float x = (k < Ksrc && n < Ncols) ? w[k * Ncols + n] : 0.0f;
            __bf16 hb = (__bf16)x;
            lo = (unsigned int)__builtin_bit_cast(u16, hb);
        }
        {
            int k = kbase + 2 * i + 1;
            float x = (k < Ksrc && n < Ncols) ? w[k * Ncols + n] : 0.0f;
            __bf16 hb = (__bf16)x;
            hi = (unsigned int)__builtin_bit_cast(u16, hb);
        }
        d[i] = lo | (hi << 16);
    }
    u32x4 pk = { d[0], d[1], d[2], d[3] };
    int dst = off + (kt * NT + nt) * 512 + lane * 8;  // bf16 elems, 16B aligned
    *reinterpret_cast<u32x4*>(ws_us + dst) = pk;
}

// ---------------------------------------------------------------------------
// feat [B,C,H,W] fp32 -> featT [B,H,W,C] bf16 (per-pixel gather = one
// contiguous 128B read). One block per (b, y) row; LDS transpose.
// ---------------------------------------------------------------------------
__global__ void prep_featT(const float* __restrict__ feat, u16* __restrict__ featT) {
    __shared__ u16 tile[128 * 66];
    int bid = blockIdx.x;
    int b = bid >> 7, y = bid & 127;
    for (int idx = threadIdx.x; idx < CC * WW; idx += 256) {
        int c = idx >> 7, x = idx & 127;
        float v = feat[(((b * CC + c) * HH + y) * WW) + x];
        __bf16 hb = (__bf16)v;
        tile[x * 66 + c] = __builtin_bit_cast(u16, hb);
    }
    __syncthreads();
    for (int idx = threadIdx.x; idx < 2048; idx += 256) {
        int x = idx >> 4, c4 = (idx & 15) * 4;
        const u16* src = tile + x * 66 + c4;
        u32x2 d;
        d[0] = (unsigned int)src[0] | ((unsigned int)src[1] << 16);
        d[1] = (unsigned int)src[2] | ((unsigned int)src[3] << 16);
        *reinterpret_cast<u32x2*>(featT + ((b * HH + y) * WW + x) * CC + c4) = d;
    }
}

// ---------------------------------------------------------------------------
// Preload 4 weight fragments (issued BEFORE a barrier so L2 latency overlaps
// the barrier wait; plain VGPR loads cross s_barrier).
// ---------------------------------------------------------------------------
__device__ __forceinline__ void preload_w(u32x4 wpre[4], const u32x4* __restrict__ wbase,
                                          int voff) {
#pragma unroll
    for (int fi = 0; fi < 4; ++fi)
        wpre[fi] = wbase[voff + fi * 64];
}

// ---------------------------------------------------------------------------
// Transposed GEMM layer, IN-PLACE: Y^T = W^T[256,K] * X^T[K,64].
// A = packed W frags (global/L2, kt-major), B = X rows from LDS buf.
// Every wave's reads complete in the kt-loop; a barrier then makes the
// in-place epilogue write safe (single 33KB buffer -> 4 blocks/CU).
// wnxt[4] is preloaded from wnb (next layer's kt=0 frags) before the barrier.
// C layout: lane holds sample st*16+(lane&15), features ft*16+(lane>>4)*4+r
// (contiguous) -> ds_write_b64.  All LDS addrs: one base VGPR + immediates.
// ---------------------------------------------------------------------------
template <int NK>
__device__ __forceinline__ void gemm_layer(u16* buf,
                                           const u32x4* __restrict__ wbase,
                                           const float* __restrict__ bias,
                                           int wave, int lane,
                                           const u32x4 wpre[4],
                                           u32x4 wnxt[4],
                                           const u32x4* __restrict__ wnb,
                                           int vnxt) {
    f32x4 acc[4][4] = {};
    const int l15 = lane & 15;
    const int qd = lane >> 4;
    const int voff = wave * 256 + lane;           // u32x4 index, fi stride 64
    const u16* xb = buf + l15 * RS + qd * 8;      // one LDS base for ALL reads
    u16* db = buf + l15 * RS + wave * 64 + qd * 4;

    u32x4 wq[3][4];
#pragma unroll
    for (int fi = 0; fi < 4; ++fi) wq[0][fi] = wpre[fi];
    if (NK > 1) {
        const u32x4* wn = wbase + 1024;
#pragma unroll
        for (int fi = 0; fi < 4; ++fi) wq[1][fi] = wn[voff + fi * 64];
    }

    bf16x8 xc[4], xn[4];
#pragma unroll
    for (int st = 0; st < 4; ++st)
        xc[st] = __builtin_bit_cast(bf16x8,
            *reinterpret_cast<const u32x4*>(xb + st * 16 * RS));

#pragma unroll
    for (int kt = 0; kt < NK; ++kt) {
        if (kt + 2 < NK) {
            const u32x4* wn = wbase + (kt + 2) * 1024;
#pragma unroll
            for (int fi = 0; fi < 4; ++fi)
                wq[(kt + 2) % 3][fi] = wn[voff + fi * 64];
        }
        if (kt + 1 < NK) {
#pragma unroll
            for (int st = 0; st < 4; ++st)
                xn[st] = __builtin_bit_cast(bf16x8,
                    *reinterpret_cast<const u32x4*>(xb + st * 16 * RS + (kt + 1) * 32));
        }
#pragma unroll
        for (int fi = 0; fi < 4; ++fi) {
            bf16x8 wf = __builtin_bit_cast(bf16x8, wq[kt % 3][fi]);
#pragma unroll
            for (int st = 0; st < 4; ++st)
                acc[fi][st] = __builtin_amdgcn_mfma_f32_16x16x32_bf16(
                    wf, xc[st], acc[fi][st], 0, 0, 0);
        }
        if (kt + 1 < NK) {
#pragma unroll
            for (int st = 0; st < 4; ++st) xc[st] = xn[st];
        }
    }

    // Next layer's kt=0 fragments: issue before the read-drain barrier so the
    // L2 latency hides under the barrier + epilogue.
#pragma unroll
    for (int fi = 0; fi < 4; ++fi) wnxt[fi] = wnb[vnxt + fi * 64];

    __syncthreads();  // all waves' reads of buf complete -> in-place write OK

    // Epilogue: bias + ReLU + bf16, one ds_write_b64 per (fi,st), imm offsets.
#pragma unroll
    for (int fi = 0; fi < 4; ++fi) {
        int fbase = (wave * 4 + fi) * 16 + qd * 4;
        f32x4 bv = *reinterpret_cast<const f32x4*>(bias + fbase);
#pragma unroll
        for (int st = 0; st < 4; ++st) {
            float v0 = fmaxf(acc[fi][st][0] + bv[0], 0.0f);
            float v1 = fmaxf(acc[fi][st][1] + bv[1], 0.0f);
            float v2 = fmaxf(acc[fi][st][2] + bv[2], 0.0f);
            float v3 = fmaxf(acc[fi][st][3] + bv[3], 0.0f);
            __bf16 h0 = (__bf16)v0, h1 = (__bf16)v1, h2 = (__bf16)v2, h3 = (__bf16)v3;
            u32x2 d;
            d[0] = (u32)__builtin_bit_cast(u16, h0) | ((u32)__builtin_bit_cast(u16, h1) << 16);
            d[1] = (u32)__builtin_bit_cast(u16, h2) | ((u32)__builtin_bit_cast(u16, h3) << 16);
            *reinterpret_cast<u32x2*>(db + st * 16 * RS + fi * 16) = d;
        }
    }
}

// ---------------------------------------------------------------------------
// Main fused kernel: 16 queries x 4 branches = 64 rows (samples) per block.
// Single 33KB activation buffer (in-place layers) -> 4 blocks/CU.
// ---------------------------------------------------------------------------
__global__ __launch_bounds__(256, 4) void liif_main(
    const float* __restrict__ coord, const float* __restrict__ cell,
    const float* __restrict__ b0, const float* __restrict__ b1,
    const float* __restrict__ b2, const float* __restrict__ b3,
    const float* __restrict__ b4,
    const u16* __restrict__ wpack, const u16* __restrict__ featT,
    float* __restrict__ out) {
    __shared__ u16 bufA[64 * RS];
    __shared__ float areasLDS[64];

    const int t = threadIdx.x;
    const int wave = t >> 6, lane = t & 63;
    const int row = t >> 2, p = t & 3;

    // ---- stage X0 (branch math + feature gather), 4 threads per row ----
    const int bq = blockIdx.x * 16 + (row >> 2);
    const int v = row & 3;
    const int b = bq >> 16;  // Q = 65536
    const float c0 = coord[bq * 2 + 0];
    const float c1 = coord[bq * 2 + 1];
    const float rc0 = cell[bq * 2 + 0] * 128.0f;
    const float rc1 = cell[bq * 2 + 1] * 128.0f;
    const float eps = 1e-6f;
    const float sx = ((v & 2) ? 0.0078125f : -0.0078125f) + eps;
    const float sy = ((v & 1) ? 0.0078125f : -0.0078125f) + eps;
    float cs0 = fminf(fmaxf(c0 + sx, -1.0f + eps), 1.0f - eps);
    float cs1 = fminf(fmaxf(c1 + sy, -1.0f + eps), 1.0f - eps);
    float fy = fminf(fmaxf(floorf((cs0 + 1.0f) * 64.0f), 0.0f), 127.0f);
    float fx = fminf(fmaxf(floorf((cs1 + 1.0f) * 64.0f), 0.0f), 127.0f);
    int iy = (int)fy, ix = (int)fx;
    float qc0 = -1.0f + (2.0f * fy + 1.0f) * 0.0078125f;
    float qc1 = -1.0f + (2.0f * fx + 1.0f) * 0.0078125f;
    float rel0 = (c0 - qc0) * 128.0f;
    float rel1 = (c1 - qc1) * 128.0f;
    float area = fabsf(rel0 * rel1) + 1e-9f;

    {
        const u16* fr = featT + (((b * HH + iy) * WW + ix) * CC) + p * 16;
        u32x4 f0 = *reinterpret_cast<const u32x4*>(fr);
        u32x4 f1 = *reinterpret_cast<const u32x4*>(fr + 8);
        u16* sb = bufA + row * RS;
        *reinterpret_cast<u32x4*>(sb + p * 16) = f0;
        *reinterpret_cast<u32x4*>(sb + p * 16 + 8) = f1;
        u32x4 e = { 0u, 0u, 0u, 0u };
        if (p == 0) {
            __bf16 h0 = (__bf16)rel0, h1 = (__bf16)rel1, h2 = (__bf16)rc0, h3 = (__bf16)rc1;
            e[0] = (u32)__builtin_bit_cast(u16, h0) | ((u32)__builtin_bit_cast(u16, h1) << 16);
            e[1] = (u32)__builtin_bit_cast(u16, h2) | ((u32)__builtin_bit_cast(u16, h3) << 16);
            areasLDS[row] = area;
        }
        *reinterpret_cast<u32x4*>(sb + 64 + p * 8) = e;  // features 64..95
    }

    const u32x4* wp = reinterpret_cast<const u32x4*>(wpack);
    const u32x4* wp0 = wp + (L0_OFF / 8);
    const u32x4* wp1 = wp + (L1_OFF / 8);
    const u32x4* wp2 = wp + (L2_OFF / 8);
    const u32x4* wp3 = wp + (L3_OFF / 8);
    const u32x4* wp4 = wp + (W4_OFF / 8);
    const int voff = wave * 256 + lane;

    u32x4 wA[4], wB[4];
    preload_w(wA, wp0, voff);
    __syncthreads();
    gemm_layer<3>(bufA, wp0, b0, wave, lane, wA, wB, wp1, voff);
    __syncthreads();
    gemm_layer<8>(bufA, wp1, b1, wave, lane, wB, wA, wp2, voff);
    __syncthreads();
    gemm_layer<8>(bufA, wp2, b2, wave, lane, wA, wB, wp3, voff);
    __syncthreads();
    // wnb = wp4 with vnxt = lane: wB[fi] <- w4 fragment kt=fi (NT=1 layout)
    gemm_layer<8>(bufA, wp3, b3, wave, lane, wB, wA, wp4, lane);
    // w4 kt=4..7 fragments
    u32x4 w4hi[4];
#pragma unroll
    for (int kt = 0; kt < 4; ++kt) w4hi[kt] = wp4[(kt + 4) * 64 + lane];
    __syncthreads();

    // ---- final layer 256->3 via MFMA; wave handles sample-tile st = wave ----
    const int l15 = lane & 15;
    const int qd = lane >> 4;
    const u16* xb = bufA + (wave * 16 + l15) * RS + qd * 8;
    f32x4 accf = {};
#pragma unroll
    for (int kt = 0; kt < 4; ++kt) {
        bf16x8 x = __builtin_bit_cast(bf16x8,
            *reinterpret_cast<const u32x4*>(xb + kt * 32));
        accf = __builtin_amdgcn_mfma_f32_16x16x32_bf16(
            __builtin_bit_cast(bf16x8, wA[kt]), x, accf, 0, 0, 0);
    }
#pragma unroll
    for (int kt = 4; kt < 8; ++kt) {
        bf16x8 x = __builtin_bit_cast(bf16x8,
            *reinterpret_cast<const u32x4*>(xb + kt * 32));
        accf = __builtin_amdgcn_mfma_f32_16x16x32_bf16(
            __builtin_bit_cast(bf16x8, w4hi[kt - 4]), x, accf, 0, 0, 0);
    }
    // lane (qd==0) holds pred[0..2] in accf[0..2] for sample = wave*16 + l15.
    float a = areasLDS[wave * 16 + l15];
    float a1 = a + __shfl_xor(a, 1);
    float asum = a1 + __shfl_xor(a1, 2);
    float aopp = __shfl_xor(a, 3);  // diagonal swap 0<->3, 1<->2
    float wgt = aopp / asum;
    float o0 = (accf[0] + b4[0]) * wgt;
    float o1 = (accf[1] + b4[1]) * wgt;
    float o2 = (accf[2] + b4[2]) * wgt;
    o0 += __shfl_xor(o0, 1); o0 += __shfl_xor(o0, 2);
    o1 += __shfl_xor(o1, 1); o1 += __shfl_xor(o1, 2);
    o2 += __shfl_xor(o2, 1); o2 += __shfl_xor(o2, 2);

    if (qd == 0 && (l15 & 3) == 0) {
        int obq = blockIdx.x * 16 + wave * 4 + (l15 >> 2);
        out[obq * 3 + 0] = o0;
        out[obq * 3 + 1] = o1;
        out[obq * 3 + 2] = o2;
    }
}

// ---------------------------------------------------------------------------
extern "C" void kernel_launch(void* const* d_in, const int* in_sizes, int n_in,
                              void* d_out, int out_size, void* d_ws, size_t ws_size,
                              hipStream_t stream) {
    const float* feat  = (const float*)d_in[0];
    const float* coord = (const float*)d_in[1];
    const float* cell  = (const float*)d_in[2];
    const float* w0 = (const float*)d_in[3];
    const float* b0 = (const float*)d_in[4];
    const float* w1 = (const float*)d_in[5];
    const float* b1 = (const float*)d_in[6];
    const float* w2 = (const float*)d_in[7];
    const float* b2 = (const float*)d_in[8];
    const float* w3 = (const float*)d_in[9];
    const float* b3 = (const float*)d_in[10];
    const float* w4 = (const float*)d_in[11];
    const float* b4 = (const float*)d_in[12];

    u16* ws_us = (u16*)d_ws;
    u16* featT = (u16*)((char*)d_ws + FEATT_BYTE_OFF);
    // ws need: 524288 + 8388608 = 8912896 bytes

    hipLaunchKernelGGL(pack_weights, dim3(440), dim3(64), 0, stream,
                       w0, w1, w2, w3, w4, ws_us);
    hipLaunchKernelGGL(prep_featT, dim3(BB * HH), dim3(256), 0, stream, feat, featT);
    hipLaunchKernelGGL(liif_main, dim3((BB * QQ) / 16), dim3(256), 0, stream,
                       coord, cell, b0, b1, b2, b3, b4, ws_us, featT,
                       (float*)d_out);
}

// Round 5
// 518.313 us; speedup vs baseline: 1.0792x; 1.0145x over previous
//
#include <hip/hip_runtime.h>
#include <cstdint>

typedef __bf16 bf16x8 __attribute__((ext_vector_type(8)));
typedef float f32x4 __attribute__((ext_vector_type(4)));
typedef unsigned int u32x4 __attribute__((ext_vector_type(4)));
typedef unsigned int u32x2 __attribute__((ext_vector_type(2)));
typedef unsigned short u16;
typedef unsigned int u32;

// Problem constants (fixed by reference)
#define HH 128
#define WW 128
#define CC 64
#define QQ 65536
#define BB 4

// LDS activation row stride in u16: 256 features + 8 pad.
// 264 u16 = 528 B = 132 words; 132 mod 32 = 4 -> row r rotates banks by 4r;
// all addresses stay ADDITIVE (ds offset immediates, no per-access VALU).
#define RS 264

// Packed-weight offsets in bf16 elements inside d_ws (kt-major fragment order)
#define L0_OFF 0        // 3 kt x 16 nt x 512  = 24576
#define L1_OFF 24576    // 8 x 16 x 512 = 65536
#define L2_OFF 90112
#define L3_OFF 155648
#define W4_OFF 221184   // 8 kt x 1 nt x 512 = 4096
#define FEATT_BYTE_OFF 524288u  // featT: 4*128*128*64 bf16 = 8388608 B

// ---------------------------------------------------------------------------
// Pack w0..w3 (+ w4 zero-padded to 16 cols) into MFMA fragment order (bf16),
// kt-major: tile index = kt*NT + nt.  Fragment (nt,kt): lane l, j=0..7 holds
//   W[kt*32 + (l>>4)*8 + j][nt*16 + (l&15)]
// Serves as B-frag of W == A-frag of W^T.  Layer 0 K padded 68 -> 96.
// ---------------------------------------------------------------------------
__global__ void pack_weights(const float* __restrict__ w0,
                             const float* __restrict__ w1,
                             const float* __restrict__ w2,
                             const float* __restrict__ w3,
                             const float* __restrict__ w4,
                             u16* __restrict__ ws_us) {
    int bid = blockIdx.x;
    int lane = threadIdx.x;  // 64
    int tile, nk, off, Ksrc, Ncols, NT;
    const float* w;
    if (bid < 48)       { tile = bid;       nk = 3; off = L0_OFF; w = w0; Ksrc = 68;  Ncols = 256; NT = 16; }
    else if (bid < 176) { tile = bid - 48;  nk = 8; off = L1_OFF; w = w1; Ksrc = 256; Ncols = 256; NT = 16; }
    else if (bid < 304) { tile = bid - 176; nk = 8; off = L2_OFF; w = w2; Ksrc = 256; Ncols = 256; NT = 16; }
    else if (bid < 432) { tile = bid - 304; nk = 8; off = L3_OFF; w = w3; Ksrc = 256; Ncols = 256; NT = 16; }
    else                { tile = bid - 432; nk = 8; off = W4_OFF; w = w4; Ksrc = 256; Ncols = 3;   NT = 1;  }
    int kt = tile % nk;
    int nt = tile / nk;
    int n = nt * 16 + (lane & 15);
    int kbase = kt * 32 + (lane >> 4) * 8;
    unsigned int d[4];
    for (int i = 0; i < 4; ++i) {
        unsigned int lo, hi;
        {
            int k = kbase + 2 * i;
            float x = (k < Ksrc && n < Ncols) ? w[k * Ncols + n] : 0.0f;
            __bf16 hb = (__bf16)x;
            lo = (unsigned int)__builtin_bit_cast(u16, hb);
        }
        {
            int k = kbase + 2 * i + 1;
            float x = (k < Ksrc && n < Ncols) ? w[k * Ncols + n] : 0.0f;
            __bf16 hb = (__bf16)x;
            hi = (unsigned int)__builtin_bit_cast(u16, hb);
        }
        d[i] = lo | (hi << 16);
    }
    u32x4 pk = { d[0], d[1], d[2], d[3] };
    int dst = off + (kt * NT + nt) * 512 + lane * 8;  // bf16 elems, 16B aligned
    *reinterpret_cast<u32x4*>(ws_us + dst) = pk;
}

// ---------------------------------------------------------------------------
// feat [B,C,H,W] fp32 -> featT [B,H,W,C] bf16 (per-pixel gather = one
// contiguous 128B read). One block per (b, y) row; LDS transpose.
// ---------------------------------------------------------------------------
__global__ void prep_featT(const float* __restrict__ feat, u16* __restrict__ featT) {
    __shared__ u16 tile[128 * 66];
    int bid = blockIdx.x;
    int b = bid >> 7, y = bid & 127;
    for (int idx = threadIdx.x; idx < CC * WW; idx += 256) {
        int c = idx >> 7, x = idx & 127;
        float v = feat[(((b * CC + c) * HH + y) * WW) + x];
        __bf16 hb = (__bf16)v;
        tile[x * 66 + c] = __builtin_bit_cast(u16, hb);
    }
    __syncthreads();
    for (int idx = threadIdx.x; idx < 2048; idx += 256) {
        int x = idx >> 4, c4 = (idx & 15) * 4;
        const u16* src = tile + x * 66 + c4;
        u32x2 d;
        d[0] = (unsigned int)src[0] | ((unsigned int)src[1] << 16);
        d[1] = (unsigned int)src[2] | ((unsigned int)src[3] << 16);
        *reinterpret_cast<u32x2*>(featT + ((b * HH + y) * WW + x) * CC + c4) = d;
    }
}

// ---------------------------------------------------------------------------
// Preload 4 weight fragments (issued BEFORE a barrier so L2 latency overlaps
// the barrier wait; plain VGPR loads cross s_barrier).
// ---------------------------------------------------------------------------
__device__ __forceinline__ void preload_w(u32x4 wpre[4], const u32x4* __restrict__ wbase,
                                          int voff) {
#pragma unroll
    for (int fi = 0; fi < 4; ++fi)
        wpre[fi] = wbase[voff + fi * 64];
}

// ---------------------------------------------------------------------------
// Transposed GEMM layer, IN-PLACE: Y^T = W^T[256,K] * X^T[K,64].
// A = packed W frags (global/L2, kt-major, ring-2 prefetch), B = X rows from
// LDS (xc[st] reloaded IN PLACE right after its 4 consuming MFMAs: the kt+1
// read issues ~12 MFMAs before use -> LDS latency hidden, no extra regs).
// Register budget (4 blocks/CU = 128/wave): acc 64 AGPR + wq 32 + xc 16 +
// addressing ~12 -> no spill.
// C layout: lane holds sample st*16+(lane&15), features ft*16+(lane>>4)*4+r
// (contiguous) -> ds_write_b64.  All LDS addrs: one base VGPR + immediates.
// ---------------------------------------------------------------------------
template <int NK>
__device__ __forceinline__ void gemm_layer(u16* buf,
                                           const u32x4* __restrict__ wbase,
                                           const float* __restrict__ bias,
                                           int wave, int lane,
                                           const u32x4 wpre[4],
                                           u32x4 wnxt[4],
                                           const u32x4* __restrict__ wnb,
                                           int vnxt) {
    f32x4 acc[4][4] = {};
    const int l15 = lane & 15;
    const int qd = lane >> 4;
    const int voff = wave * 256 + lane;           // u32x4 index, fi stride 64
    const u16* xb = buf + l15 * RS + qd * 8;      // one LDS base for ALL reads
    u16* db = buf + l15 * RS + wave * 64 + qd * 4;

    u32x4 wq[2][4];
#pragma unroll
    for (int fi = 0; fi < 4; ++fi) wq[0][fi] = wpre[fi];

    bf16x8 xc[4];
#pragma unroll
    for (int st = 0; st < 4; ++st)
        xc[st] = __builtin_bit_cast(bf16x8,
            *reinterpret_cast<const u32x4*>(xb + st * 16 * RS));

#pragma unroll
    for (int kt = 0; kt < NK; ++kt) {
        if (kt + 1 < NK) {
            const u32x4* wn = wbase + (kt + 1) * 1024;
#pragma unroll
            for (int fi = 0; fi < 4; ++fi)
                wq[(kt + 1) & 1][fi] = wn[voff + fi * 64];
        }
#pragma unroll
        for (int st = 0; st < 4; ++st) {
#pragma unroll
            for (int fi = 0; fi < 4; ++fi)
                acc[fi][st] = __builtin_amdgcn_mfma_f32_16x16x32_bf16(
                    __builtin_bit_cast(bf16x8, wq[kt & 1][fi]), xc[st],
                    acc[fi][st], 0, 0, 0);
            if (kt + 1 < NK)
                xc[st] = __builtin_bit_cast(bf16x8,
                    *reinterpret_cast<const u32x4*>(xb + st * 16 * RS + (kt + 1) * 32));
        }
    }

    // Next layer's kt=0 fragments: issue before the read-drain barrier so the
    // L2 latency hides under the barrier + epilogue.
#pragma unroll
    for (int fi = 0; fi < 4; ++fi) wnxt[fi] = wnb[vnxt + fi * 64];

    __syncthreads();  // all waves' reads of buf complete -> in-place write OK

    // Epilogue: bias + ReLU + bf16, one ds_write_b64 per (fi,st), imm offsets.
#pragma unroll
    for (int fi = 0; fi < 4; ++fi) {
        int fbase = (wave * 4 + fi) * 16 + qd * 4;
        f32x4 bv = *reinterpret_cast<const f32x4*>(bias + fbase);
#pragma unroll
        for (int st = 0; st < 4; ++st) {
            float v0 = fmaxf(acc[fi][st][0] + bv[0], 0.0f);
            float v1 = fmaxf(acc[fi][st][1] + bv[1], 0.0f);
            float v2 = fmaxf(acc[fi][st][2] + bv[2], 0.0f);
            float v3 = fmaxf(acc[fi][st][3] + bv[3], 0.0f);
            __bf16 h0 = (__bf16)v0, h1 = (__bf16)v1, h2 = (__bf16)v2, h3 = (__bf16)v3;
            u32x2 d;
            d[0] = (u32)__builtin_bit_cast(u16, h0) | ((u32)__builtin_bit_cast(u16, h1) << 16);
            d[1] = (u32)__builtin_bit_cast(u16, h2) | ((u32)__builtin_bit_cast(u16, h3) << 16);
            *reinterpret_cast<u32x2*>(db + st * 16 * RS + fi * 16) = d;
        }
    }
}

// ---------------------------------------------------------------------------
// Main fused kernel: 16 queries x 4 branches = 64 rows (samples) per block.
// Single 33KB activation buffer (in-place layers) -> 4 blocks/CU.
// ---------------------------------------------------------------------------
__global__ __launch_bounds__(256, 4) void liif_main(
    const float* __restrict__ coord, const float* __restrict__ cell,
    const float* __restrict__ b0, const float* __restrict__ b1,
    const float* __restrict__ b2, const float* __restrict__ b3,
    const float* __restrict__ b4,
    const u16* __restrict__ wpack, const u16* __restrict__ featT,
    float* __restrict__ out) {
    __shared__ u16 bufA[64 * RS];
    __shared__ float areasLDS[64];

    const int t = threadIdx.x;
    const int wave = t >> 6, lane = t & 63;
    const int row = t >> 2, p = t & 3;

    // ---- stage X0 (branch math + feature gather), 4 threads per row ----
    const int bq = blockIdx.x * 16 + (row >> 2);
    const int v = row & 3;
    const int b = bq >> 16;  // Q = 65536
    const float c0 = coord[bq * 2 + 0];
    const float c1 = coord[bq * 2 + 1];
    const float rc0 = cell[bq * 2 + 0] * 128.0f;
    const float rc1 = cell[bq * 2 + 1] * 128.0f;
    const float eps = 1e-6f;
    const float sx = ((v & 2) ? 0.0078125f : -0.0078125f) + eps;
    const float sy = ((v & 1) ? 0.0078125f : -0.0078125f) + eps;
    float cs0 = fminf(fmaxf(c0 + sx, -1.0f + eps), 1.0f - eps);
    float cs1 = fminf(fmaxf(c1 + sy, -1.0f + eps), 1.0f - eps);
    float fy = fminf(fmaxf(floorf((cs0 + 1.0f) * 64.0f), 0.0f), 127.0f);
    float fx = fminf(fmaxf(floorf((cs1 + 1.0f) * 64.0f), 0.0f), 127.0f);
    int iy = (int)fy, ix = (int)fx;
    float qc0 = -1.0f + (2.0f * fy + 1.0f) * 0.0078125f;
    float qc1 = -1.0f + (2.0f * fx + 1.0f) * 0.0078125f;
    float rel0 = (c0 - qc0) * 128.0f;
    float rel1 = (c1 - qc1) * 128.0f;
    float area = fabsf(rel0 * rel1) + 1e-9f;

    {
        const u16* fr = featT + (((b * HH + iy) * WW + ix) * CC) + p * 16;
        u32x4 f0 = *reinterpret_cast<const u32x4*>(fr);
        u32x4 f1 = *reinterpret_cast<const u32x4*>(fr + 8);
        u16* sb = bufA + row * RS;
        *reinterpret_cast<u32x4*>(sb + p * 16) = f0;
        *reinterpret_cast<u32x4*>(sb + p * 16 + 8) = f1;
        u32x4 e = { 0u, 0u, 0u, 0u };
        if (p == 0) {
            __bf16 h0 = (__bf16)rel0, h1 = (__bf16)rel1, h2 = (__bf16)rc0, h3 = (__bf16)rc1;
            e[0] = (u32)__builtin_bit_cast(u16, h0) | ((u32)__builtin_bit_cast(u16, h1) << 16);
            e[1] = (u32)__builtin_bit_cast(u16, h2) | ((u32)__builtin_bit_cast(u16, h3) << 16);
            areasLDS[row] = area;
        }
        *reinterpret_cast<u32x4*>(sb + 64 + p * 8) = e;  // features 64..95
    }

    const u32x4* wp = reinterpret_cast<const u32x4*>(wpack);
    const u32x4* wp0 = wp + (L0_OFF / 8);
    const u32x4* wp1 = wp + (L1_OFF / 8);
    const u32x4* wp2 = wp + (L2_OFF / 8);
    const u32x4* wp3 = wp + (L3_OFF / 8);
    const u32x4* wp4 = wp + (W4_OFF / 8);
    const int voff = wave * 256 + lane;

    u32x4 wA[4], wB[4];
    preload_w(wA, wp0, voff);
    __syncthreads();
    gemm_layer<3>(bufA, wp0, b0, wave, lane, wA, wB, wp1, voff);
    __syncthreads();
    gemm_layer<8>(bufA, wp1, b1, wave, lane, wB, wA, wp2, voff);
    __syncthreads();
    gemm_layer<8>(bufA, wp2, b2, wave, lane, wA, wB, wp3, voff);
    __syncthreads();
    // wnb = wp4 with vnxt = lane: wB[fi] <- w4 fragment kt=fi (NT=1 layout)
    gemm_layer<8>(bufA, wp3, b3, wave, lane, wB, wA, wp4, lane);
    // w4 kt=4..7 fragments
    u32x4 w4hi[4];
#pragma unroll
    for (int kt = 0; kt < 4; ++kt) w4hi[kt] = wp4[(kt + 4) * 64 + lane];
    __syncthreads();

    // ---- final layer 256->3 via MFMA; wave handles sample-tile st = wave ----
    const int l15 = lane & 15;
    const int qd = lane >> 4;
    const u16* xb = bufA + (wave * 16 + l15) * RS + qd * 8;
    f32x4 accf = {};
#pragma unroll
    for (int kt = 0; kt < 4; ++kt) {
        bf16x8 x = __builtin_bit_cast(bf16x8,
            *reinterpret_cast<const u32x4*>(xb + kt * 32));
        accf = __builtin_amdgcn_mfma_f32_16x16x32_bf16(
            __builtin_bit_cast(bf16x8, wA[kt]), x, accf, 0, 0, 0);
    }
#pragma unroll
    for (int kt = 4; kt < 8; ++kt) {
        bf16x8 x = __builtin_bit_cast(bf16x8,
            *reinterpret_cast<const u32x4*>(xb + kt * 32));
        accf = __builtin_amdgcn_mfma_f32_16x16x32_bf16(
            __builtin_bit_cast(bf16x8, w4hi[kt - 4]), x, accf, 0, 0, 0);
    }
    // lane (qd==0) holds pred[0..2] in accf[0..2] for sample = wave*16 + l15.
    float a = areasLDS[wave * 16 + l15];
    float a1 = a + __shfl_xor(a, 1);
    float asum = a1 + __shfl_xor(a1, 2);
    float aopp = __shfl_xor(a, 3);  // diagonal swap 0<->3, 1<->2
    float wgt = aopp / asum;
    float o0 = (accf[0] + b4[0]) * wgt;
    float o1 = (accf[1] + b4[1]) * wgt;
    float o2 = (accf[2] + b4[2]) * wgt;
    o0 += __shfl_xor(o0, 1); o0 += __shfl_xor(o0, 2);
    o1 += __shfl_xor(o1, 1); o1 += __shfl_xor(o1, 2);
    o2 += __shfl_xor(o2, 1); o2 += __shfl_xor(o2, 2);

    if (qd == 0 && (l15 & 3) == 0) {
        int obq = blockIdx.x * 16 + wave * 4 + (l15 >> 2);
        out[obq * 3 + 0] = o0;
        out[obq * 3 + 1] = o1;
        out[obq * 3 + 2] = o2;
    }
}

// ---------------------------------------------------------------------------
extern "C" void kernel_launch(void* const* d_in, const int* in_sizes, int n_in,
                              void* d_out, int out_size, void* d_ws, size_t ws_size,
                              hipStream_t stream) {
    const float* feat  = (const float*)d_in[0];
    const float* coord = (const float*)d_in[1];
    const float* cell  = (const float*)d_in[2];
    const float* w0 = (const float*)d_in[3];
    const float* b0 = (const float*)d_in[4];
    const float* w1 = (const float*)d_in[5];
    const float* b1 = (const float*)d_in[6];
    const float* w2 = (const float*)d_in[7];
    const float* b2 = (const float*)d_in[8];
    const float* w3 = (const float*)d_in[9];
    const float* b3 = (const float*)d_in[10];
    const float* w4 = (const float*)d_in[11];
    const float* b4 = (const float*)d_in[12];

    u16* ws_us = (u16*)d_ws;
    u16* featT = (u16*)((char*)d_ws + FEATT_BYTE_OFF);
    // ws need: 524288 + 8388608 = 8912896 bytes

    hipLaunchKernelGGL(pack_weights, dim3(440), dim3(64), 0, stream,
                       w0, w1, w2, w3, w4, ws_us);
    hipLaunchKernelGGL(prep_featT, dim3(BB * HH), dim3(256), 0, stream, feat, featT);
    hipLaunchKernelGGL(liif_main, dim3((BB * QQ) / 16), dim3(256), 0, stream,
                       coord, cell, b0, b1, b2, b3, b4, ws_us, featT,
                       (float*)d_out);
}